// Round 6
// baseline (110.087 us; speedup 1.0000x reference)
//
#include <hip/hip_runtime.h>
#include <math.h>

#define HH 256
#define WW 256
static constexpr int HW = HH * WW;
static constexpr float MIN_D = 0.1f;
static constexpr float MAX_D = 10.0f;
static constexpr float C1c = 1e-4f;   // 0.01^2
static constexpr float C2c = 9e-4f;   // 0.03^2
static constexpr float ZW_SCALE = 1048576.f;   // 2^20
static constexpr float W_SCALE  = 4194304.f;   // 2^22

__device__ inline unsigned shdu(unsigned v, int o) {
    return (unsigned)__shfl_down((int)v, o, 64);
}

// ---------------------------------------------------------------------------
// Stage 0: zero the u64 accumulator (16B stores) + init mm/accum/ticket.
// ---------------------------------------------------------------------------
__global__ __launch_bounds__(256) void zero_k(ulonglong2* __restrict__ accv,
                          unsigned* __restrict__ mm, float* __restrict__ accum,
                          unsigned* __restrict__ ticket, int n16) {
    int i = blockIdx.x * 256 + threadIdx.x;
    if (i < n16) accv[i] = ulonglong2{0ull, 0ull};
    if (blockIdx.x == 0) {
        int tt = threadIdx.x;
        if (tt < 8) mm[tt] = 0xFFFFFFFFu;                 // minP, minG slots
        else if (tt < 16) mm[tt] = 0u;                    // maxP, maxG slots
        else if (tt < 19) accum[tt - 16] = 0.f;           // ssim/mask/l1 sums
        else if (tt == 19) *ticket = 0u;
    }
}

// ---------------------------------------------------------------------------
// Stage 1: weighted z-buffer scatter, LDS-staged. Each 256-thread block owns
// 2048 consecutive points: stages 24KB pts + 8KB dens via global_load_lds
// dwordx4 (dense 1KB per wave-issue, 8 issues/wave total), then each thread
// processes 8 points read from LDS at stride-3 dwords (2-way aliasing: free).
// One u64 fixed-point atomic per valid point (hi=zw*2^20, lo=w*2^22).
// Tail chunks are exactly 1024B-aligned (96e6 and 32e6 are multiples of 1024
// against 24576/8192-strided bases) and zero-filled -> z=0 -> skipped.
// ---------------------------------------------------------------------------
__global__ __launch_bounds__(256) void scatter_k(const char* __restrict__ ptsB,
                          const char* __restrict__ densB,
                          unsigned long long* __restrict__ acc,
                          int N, int total) {
    __shared__ float shp[6144];    // 2048 pts * {x,y,z}
    __shared__ float shd[2048];    // 2048 densities
    int tid = threadIdx.x;
    int wave = tid >> 6, lane = tid & 63;
    char* shpB = (char*)shp;
    char* shdB = (char*)shd;
    long long pbase = (long long)blockIdx.x * 24576;
    long long dbase = (long long)blockIdx.x * 8192;
    long long plim = (long long)total * 12;
    long long dlim = (long long)total * 4;

#pragma unroll
    for (int i = 0; i < 6; ++i) {               // pts: 24 chunks, 6 per wave
        int off = (wave * 6 + i) << 10;
        long long g = pbase + off;
        if (g + 1024 <= plim) {
            __builtin_amdgcn_global_load_lds((const void*)(ptsB + g + (lane << 4)),
                                             (void*)(shpB + off), 16, 0, 0);
        } else {
            *(float4*)(shpB + off + (lane << 4)) = float4{0.f, 0.f, 0.f, 0.f};
        }
    }
#pragma unroll
    for (int i = 0; i < 2; ++i) {               // dens: 8 chunks, 2 per wave
        int off = (wave * 2 + i) << 10;
        long long g = dbase + off;
        if (g + 1024 <= dlim) {
            __builtin_amdgcn_global_load_lds((const void*)(densB + g + (lane << 4)),
                                             (void*)(shdB + off), 16, 0, 0);
        } else {
            *(float4*)(shdB + off + (lane << 4)) = float4{0.f, 0.f, 0.f, 0.f};
        }
    }
    __syncthreads();                            // drains vmcnt + lgkmcnt

    int p0 = blockIdx.x << 11;
    int N2 = N << 1, N3 = N * 3;
#pragma unroll
    for (int k = 0; k < 8; ++k) {
        int q = tid + (k << 8);                 // stride-256: 2-way LDS aliasing
        float z = shp[3 * q + 2];
        if (!(z > MIN_D)) continue;             // strict z > MIN_DEPTH
        float x = shp[3 * q], y = shp[3 * q + 1];
        float invz = __builtin_amdgcn_rcpf(z);
        invz = invz * (2.0f - z * invz);        // Newton -> ~1 ulp of 1/z
        float u = (x * invz + 0.5f) * (float)WW;
        float v = (y * invz + 0.5f) * (float)HH;
        if (!(u >= 0.f && u < (float)WW && v >= 0.f && v < (float)HH)) continue;
        int ui = (int)u;                        // trunc == floor (u >= 0)
        int vi = (int)v;
        float w = __builtin_amdgcn_rcpf(1.f + __expf(-shd[q]));  // sigmoid
        unsigned hi = (unsigned)__float2int_rn(z * w * ZW_SCALE);
        unsigned lo = (unsigned)__float2int_rn(w * W_SCALE);
        unsigned long long pk = ((unsigned long long)hi << 32) | lo;
        int p = p0 + q;
        int b = (p >= N) + (p >= N2) + (p >= N3);   // batch (blocks may straddle)
        atomicAdd(&acc[b * HW + ((vi << 8) | ui)], pk);
    }
}

// ---------------------------------------------------------------------------
// Stage 2: depth = (hi/lo)*4 (where lo>0) -> raw; per-batch min/max of valid
// pred & gt via uint-bit atomics.
// mm layout: [0..3]=minP, [4..7]=minG, [8..11]=maxP, [12..15]=maxG
// ---------------------------------------------------------------------------
__global__ __launch_bounds__(256) void finalize_k(const unsigned long long* __restrict__ acc,
                           const float* __restrict__ gt, float* __restrict__ raw,
                           unsigned* __restrict__ mm) {
    int i = blockIdx.x * 256 + threadIdx.x;
    int b = blockIdx.x >> 8;
    unsigned long long v = acc[i];
    unsigned lo = (unsigned)v;
    unsigned hi = (unsigned)(v >> 32);
    float d = lo ? ((float)hi / (float)lo) * 4.0f : 0.f;   // (hi/2^20)/(lo/2^22)
    raw[i] = d;
    float g = gt[i];
    unsigned dmin = d > 0.f ? __float_as_uint(d) : 0xFFFFFFFFu;
    unsigned dmax = d > 0.f ? __float_as_uint(d) : 0u;
    unsigned gmin = g > 0.f ? __float_as_uint(g) : 0xFFFFFFFFu;
    unsigned gmax = g > 0.f ? __float_as_uint(g) : 0u;
    for (int o = 32; o; o >>= 1) {
        dmin = min(dmin, shdu(dmin, o));
        gmin = min(gmin, shdu(gmin, o));
        dmax = max(dmax, shdu(dmax, o));
        gmax = max(gmax, shdu(gmax, o));
    }
    __shared__ unsigned sm[4][4];
    int wid = threadIdx.x >> 6, lane = threadIdx.x & 63;
    if (lane == 0) { sm[0][wid] = dmin; sm[1][wid] = gmin; sm[2][wid] = dmax; sm[3][wid] = gmax; }
    __syncthreads();
    if (threadIdx.x == 0) {
        unsigned m0 = min(min(sm[0][0], sm[0][1]), min(sm[0][2], sm[0][3]));
        unsigned m1 = min(min(sm[1][0], sm[1][1]), min(sm[1][2], sm[1][3]));
        unsigned m2 = max(max(sm[2][0], sm[2][1]), max(sm[2][2], sm[2][3]));
        unsigned m3 = max(max(sm[3][0], sm[3][1]), max(sm[3][2], sm[3][3]));
        atomicMin(&mm[b], m0);
        atomicMin(&mm[4 + b], m1);
        atomicMax(&mm[8 + b], m2);
        atomicMax(&mm[12 + b], m3);
    }
}

// ---------------------------------------------------------------------------
// Stage 3: fused normalize + separable 11x11 zero-padded box SSIM + masked L1
// + final combine (last block via atomic ticket). Row-band structure.
// accum[0]=ssim_sum, accum[1]=mask_sum, accum[2]=l1_sum
// ---------------------------------------------------------------------------
__global__ __launch_bounds__(256) void ssim_k(const float* __restrict__ raw,
                       const float* __restrict__ gt, const unsigned* __restrict__ mm,
                       float* __restrict__ accum, unsigned* __restrict__ ticket,
                       float* __restrict__ out, int nblocks) {
    __shared__ float hs[5][266];
    __shared__ float sb[3][4];
    int z = blockIdx.y;
    int r0 = blockIdx.x * 4;
    int tx = threadIdx.x;
    const float* P = raw + (size_t)z * HW;
    const float* T = gt + (size_t)z * HW;

    bool hasP = mm[8 + z] != 0u;
    float pmin_m = hasP ? fmaxf(__uint_as_float(mm[z]), MIN_D) : 0.f;
    float pscale = 1.f / ((hasP ? fminf(__uint_as_float(mm[8 + z]), MAX_D) : MAX_D) - pmin_m + 1e-8f);
    bool hasG = mm[12 + z] != 0u;
    float gmin_m = hasG ? fmaxf(__uint_as_float(mm[4 + z]), MIN_D) : 0.f;
    float gscale = 1.f / ((hasG ? fminf(__uint_as_float(mm[12 + z]), MAX_D) : MAX_D) - gmin_m + 1e-8f);

    // 14 rows (r0-5 .. r0+8), normalized; out-of-image rows -> 0 (zero-pad)
    float p[14], t[14];
#pragma unroll
    for (int i = 0; i < 14; ++i) {
        int row = r0 - 5 + i;
        bool ok = (row >= 0) && (row < HH);
        float dv = ok ? P[row * WW + tx] : 0.f;
        float gv = ok ? T[row * WW + tx] : 0.f;
        p[i] = (dv - pmin_m) * pscale * (dv > 0.f ? 1.f : 0.f);
        t[i] = (gv - gmin_m) * gscale * (gv > 0.f ? 1.f : 0.f);
    }
    if (tx < 5) {
#pragma unroll
        for (int q = 0; q < 5; ++q) { hs[q][tx] = 0.f; hs[q][261 + tx] = 0.f; }
    }
    __syncthreads();

    const float inv121 = 1.f / 121.f;
    float svA = 0.f, mA = 0.f, lvA = 0.f;
#pragma unroll
    for (int r = 0; r < 4; ++r) {
        float s1 = 0, s2 = 0, s11 = 0, s22 = 0, s12 = 0;
#pragma unroll
        for (int k = 0; k < 11; ++k) {
            float pp = p[r + k], tt = t[r + k];
            s1 += pp; s2 += tt;
            s11 = fmaf(pp, pp, s11); s22 = fmaf(tt, tt, s22); s12 = fmaf(pp, tt, s12);
        }
        hs[0][5 + tx] = s1; hs[1][5 + tx] = s2; hs[2][5 + tx] = s11;
        hs[3][5 + tx] = s22; hs[4][5 + tx] = s12;
        __syncthreads();
        float h1 = 0, h2 = 0, h11 = 0, h22 = 0, h12 = 0;
#pragma unroll
        for (int k = 0; k < 11; ++k) {
            h1 += hs[0][tx + k]; h2 += hs[1][tx + k]; h11 += hs[2][tx + k];
            h22 += hs[3][tx + k]; h12 += hs[4][tx + k];
        }
        float mu1 = h1 * inv121, mu2 = h2 * inv121;
        float mu1sq = mu1 * mu1, mu2sq = mu2 * mu2, mu12 = mu1 * mu2;
        float sig1 = h11 * inv121 - mu1sq;
        float sig2 = h22 * inv121 - mu2sq;
        float sig12 = h12 * inv121 - mu12;
        float smap = (2.f * mu12 + C1c) * (2.f * sig12 + C2c) /
                     ((mu1sq + mu2sq + C1c) * (sig1 + sig2 + C2c));
        float pc = p[r + 5], tc = t[r + 5];
        float m = (pc > 0.f && tc > 0.f) ? 1.f : 0.f;
        svA += smap * m;
        mA  += m;
        lvA += m * fabsf(pc - tc);
        __syncthreads();
    }

    for (int o = 32; o; o >>= 1) {
        svA += __shfl_down(svA, o, 64);
        mA  += __shfl_down(mA, o, 64);
        lvA += __shfl_down(lvA, o, 64);
    }
    int wid = tx >> 6, lane = tx & 63;
    if (lane == 0) { sb[0][wid] = svA; sb[1][wid] = mA; sb[2][wid] = lvA; }
    __syncthreads();
    if (tx == 0) {
        unsafeAtomicAdd(&accum[0], sb[0][0] + sb[0][1] + sb[0][2] + sb[0][3]);
        unsafeAtomicAdd(&accum[1], sb[1][0] + sb[1][1] + sb[1][2] + sb[1][3]);
        unsafeAtomicAdd(&accum[2], sb[2][0] + sb[2][1] + sb[2][2] + sb[2][3]);
        __threadfence();                       // drain our adds
        unsigned old = atomicAdd(ticket, 1u);
        if (old == (unsigned)(nblocks - 1)) {  // last block: all adds visible
            __threadfence();
            float ss = __hip_atomic_load(&accum[0], __ATOMIC_RELAXED, __HIP_MEMORY_SCOPE_AGENT);
            float ms = __hip_atomic_load(&accum[1], __ATOMIC_RELAXED, __HIP_MEMORY_SCOPE_AGENT);
            float ls = __hip_atomic_load(&accum[2], __ATOMIC_RELAXED, __HIP_MEMORY_SCOPE_AGENT);
            float l1   = ls / (ms + 1e-8f);
            float ssim = 1.f - ss / (ms + 1e-8f);
            float total = fminf(0.8f * l1 + 0.2f * ssim, 1.0f);
            out[0] = (ms < 10.f) ? 0.f : total;
        }
    }
}

extern "C" void kernel_launch(void* const* d_in, const int* in_sizes, int n_in,
                              void* d_out, int out_size, void* d_ws, size_t ws_size,
                              hipStream_t stream) {
    const float* pts = (const float*)d_in[0];
    const float* dens = (const float*)d_in[1];
    const float* gt = (const float*)d_in[2];
    int B = in_sizes[2] / HW;      // 4
    int N = in_sizes[1] / B;       // 2,000,000
    int total = B * N;             // 8,000,000

    unsigned long long* acc = (unsigned long long*)d_ws;          // [B*HW] u64
    float* raw  = (float*)(acc + (size_t)B * HW);                 // [B*HW] f32
    unsigned* mm = (unsigned*)(raw + (size_t)B * HW);             // 16 u32
    float* accum = (float*)(mm + 16);                             // 3 f32
    unsigned* ticket = (unsigned*)(accum + 3);                    // 1 u32

    int n16 = B * HW / 2;                      // ulonglong2 count
    zero_k<<<(n16 + 255) / 256, 256, 0, stream>>>((ulonglong2*)acc, mm, accum,
                                                  ticket, n16);

    int nsblk = (total + 2047) / 2048;         // 2048 consecutive pts / block
    scatter_k<<<nsblk, 256, 0, stream>>>((const char*)pts, (const char*)dens,
                                         acc, N, total);
    finalize_k<<<B * 256, 256, 0, stream>>>(acc, gt, raw, mm);
    int nblocks = 64 * B;
    ssim_k<<<dim3(64, B), 256, 0, stream>>>(raw, gt, mm, accum, ticket,
                                            (float*)d_out, nblocks);
}